// Round 1
// baseline (16557.768 us; speedup 1.0000x reference)
//
#include <hip/hip_runtime.h>
#include <math.h>

// ---- problem dims ----
#define B_    32
#define D_    384
#define DEPTH 24
#define DI    768
#define DS    16
#define DCONV 4
#define DTR   24
#define L_    197
#define NCLS  1000
#define NTOK  (B_*L_)   // 6304

__device__ __forceinline__ float sigmoidf_(float x){ return 1.f/(1.f+expf(-x)); }
__device__ __forceinline__ float softplusf_(float x){ return (x>20.f)? x : log1pf(expf(x)); }

// ---------------- patch embedding + cls + pos ----------------
// grid (197, B_), block 384.  p==0 writes the cls row.
__global__ void patch_embed_kernel(const float* __restrict__ x, const float* __restrict__ pw,
                                   const float* __restrict__ pb, const float* __restrict__ cls,
                                   const float* __restrict__ pos, float* __restrict__ tok)
{
    __shared__ float patch[768];
    const int p = blockIdx.x;          // 0..196, 0 = cls token
    const int b = blockIdx.y;
    const int t = threadIdx.x;         // 0..383 = output channel d
    if (p == 0) {
        tok[((long)b*L_)*D_ + t] = cls[t] + pos[t];
        return;
    }
    const int pi = p - 1, ph = pi/14, pwc = pi%14;
    for (int i = t; i < 768; i += 384) {
        int c = i >> 8, rem = i & 255, ii = rem >> 4, jj = rem & 15;
        patch[i] = x[(((long)b*3 + c)*224 + (ph*16 + ii))*224 + pwc*16 + jj];
    }
    __syncthreads();
    float acc = pb[t];
    const float* wr = pw + (long)t*768;   // patch_w[d, c, i, j] flat
    #pragma unroll 4
    for (int k = 0; k < 768; ++k) acc += patch[k]*wr[k];
    tok[((long)b*L_ + p)*D_ + t] = acc + pos[p*D_ + t];
}

// ---------------- layernorm over last dim 384, one wave per row ----------------
// block (64,4)
__global__ void ln_kernel(const float* __restrict__ x, const float* __restrict__ w,
                          const float* __restrict__ b, float* __restrict__ out,
                          int rows, int xstride, int ostride)
{
    const int row = blockIdx.x*blockDim.y + threadIdx.y;
    if (row >= rows) return;
    const int lane = threadIdx.x;
    const float* xr = x + (long)row*xstride;
    float v[6]; float s = 0.f;
    #pragma unroll
    for (int i = 0; i < 6; ++i) { v[i] = xr[lane + 64*i]; s += v[i]; }
    #pragma unroll
    for (int o = 32; o; o >>= 1) s += __shfl_xor(s, o, 64);
    const float mu = s * (1.f/384.f);
    float var = 0.f;
    #pragma unroll
    for (int i = 0; i < 6; ++i) { float d = v[i]-mu; var += d*d; }
    #pragma unroll
    for (int o = 32; o; o >>= 1) var += __shfl_xor(var, o, 64);
    const float rstd = rsqrtf(var*(1.f/384.f) + 1e-5f);
    float* orow = out + (long)row*ostride;
    #pragma unroll
    for (int i = 0; i < 6; ++i) { int c = lane + 64*i; orow[c] = (v[i]-mu)*rstd*w[c] + b[c]; }
}

// ---------------- fp32 tiled GEMM:  C[m,n] (+)= sum_k A[m,K] * B[n,K]  (NT) ----------------
// 64x64 tile, BK=16, 256 threads, 4x4 per thread.
__global__ __launch_bounds__(256)
void gemm_nt_kernel(const float* __restrict__ A, const float* __restrict__ Bw,
                    float* __restrict__ C, int M, int N, int K, int accumulate)
{
    __shared__ float As[16][68];   // [k][m], +4 pad keeps 16B alignment, 2-way banks (free)
    __shared__ float Bs[16][68];   // [k][n]
    const int tid = threadIdx.x;
    const int bm = blockIdx.x * 64;
    const int bn = blockIdx.y * 64;
    const int tx = tid & 15, ty = tid >> 4;
    float acc[4][4] = {};
    for (int k0 = 0; k0 < K; k0 += 16) {
        #pragma unroll
        for (int i = 0; i < 4; ++i) {
            int idx = tid + i*256;
            int r = idx >> 4, c = idx & 15;
            int gm = bm + r;
            As[c][r] = (gm < M) ? A[(long)gm*K + k0 + c] : 0.f;
            int gn = bn + r;
            Bs[c][r] = (gn < N) ? Bw[(long)gn*K + k0 + c] : 0.f;
        }
        __syncthreads();
        #pragma unroll
        for (int kk = 0; kk < 16; ++kk) {
            float a[4], bb[4];
            #pragma unroll
            for (int i = 0; i < 4; ++i) a[i] = As[kk][ty*4 + i];
            #pragma unroll
            for (int j = 0; j < 4; ++j) bb[j] = Bs[kk][tx*4 + j];
            #pragma unroll
            for (int i = 0; i < 4; ++i)
                #pragma unroll
                for (int j = 0; j < 4; ++j)
                    acc[i][j] += a[i]*bb[j];
        }
        __syncthreads();
    }
    #pragma unroll
    for (int i = 0; i < 4; ++i) {
        int gm = bm + ty*4 + i;
        if (gm >= M) continue;
        #pragma unroll
        for (int j = 0; j < 4; ++j) {
            int gn = bn + tx*4 + j;
            if (gn >= N) continue;
            long idx = (long)gm*N + gn;
            if (accumulate) C[idx] += acc[i][j];
            else            C[idx] = acc[i][j];
        }
    }
}

// ---------------- causal depthwise conv1d (DCONV=4) + bias + silu ----------------
__global__ void conv_silu_kernel(const float* __restrict__ xz, const float* __restrict__ cw,
                                 const float* __restrict__ cb, float* __restrict__ out)
{
    const int idx = blockIdx.x*256 + threadIdx.x;      // (b*L + l)*DI + di
    if (idx >= NTOK*DI) return;
    const int di = idx % DI;
    const int bl = idx / DI;
    const int l  = bl % L_;
    const long rowbase = (long)(bl - l) * (2*DI) + di; // xb lives in xz[:, 0:DI]
    const float w0 = cw[di*4], w1 = cw[di*4+1], w2 = cw[di*4+2], w3 = cw[di*4+3];
    float acc = cb[di];
    if (l >= 3) acc += w0 * xz[rowbase + (long)(l-3)*(2*DI)];
    if (l >= 2) acc += w1 * xz[rowbase + (long)(l-2)*(2*DI)];
    if (l >= 1) acc += w2 * xz[rowbase + (long)(l-1)*(2*DI)];
    acc += w3 * xz[rowbase + (long)l*(2*DI)];
    out[idx] = acc * sigmoidf_(acc);                   // silu
}

// ---------------- x_proj: [NTOK,768] x [56,768]^T -> [NTOK,56]  (one row per block) ----------------
__global__ void xproj_kernel(const float* __restrict__ xbc, const float* __restrict__ xpw,
                             float* __restrict__ xdbl)
{
    __shared__ float row[768];
    const int m = blockIdx.x;
    const float* xr = xbc + (long)m*DI;
    for (int i = threadIdx.x; i < DI; i += 64) row[i] = xr[i];
    __syncthreads();
    const int e = threadIdx.x;
    if (e < DTR + 2*DS) {
        const float* wr = xpw + e*DI;
        float acc = 0.f;
        #pragma unroll 4
        for (int k = 0; k < DI; ++k) acc += row[k]*wr[k];
        xdbl[(long)m*(DTR + 2*DS) + e] = acc;
    }
}

// ---------------- dt = softplus(xdbl[:, :24] @ dtw^T + dtb) ----------------
__global__ void dtproj_kernel(const float* __restrict__ xdbl, const float* __restrict__ dtw,
                              const float* __restrict__ dtb, float* __restrict__ dt)
{
    const int idx = blockIdx.x*256 + threadIdx.x;      // m*DI + di
    if (idx >= NTOK*DI) return;
    const int di = idx % DI;
    const int m  = idx / DI;
    const float* xr = xdbl + (long)m*(DTR + 2*DS);
    const float* wr = dtw + di*DTR;
    float acc = dtb[di];
    #pragma unroll
    for (int r = 0; r < DTR; ++r) acc += xr[r]*wr[r];
    dt[idx] = softplusf_(acc);
}

// ---------------- selective scan fused with dA/dBx construction, gate, D-skip ----------------
// grid (12, B_), block 256 = 64 di-lanes x 4 s-groups (4 states each)
__global__ void scan_kernel(const float* __restrict__ dt, const float* __restrict__ xbc,
                            const float* __restrict__ xdbl, const float* __restrict__ xz,
                            const float* __restrict__ A_log, const float* __restrict__ Dp,
                            float* __restrict__ y)
{
    const int dil = threadIdx.x & 63;
    const int sg  = threadIdx.x >> 6;          // 0..3
    const int di  = blockIdx.x*64 + dil;
    const int b   = blockIdx.y;
    float A_[4], h[4] = {0.f, 0.f, 0.f, 0.f};
    #pragma unroll
    for (int i = 0; i < 4; ++i) A_[i] = -expf(A_log[di*DS + sg*4 + i]);
    const float Dpv = Dp[di];
    __shared__ float part[3][64];
    for (int l = 0; l < L_; ++l) {
        const long blo = (long)b*L_ + l;
        const float dtv = dt[blo*DI + di];
        const float xv  = xbc[blo*DI + di];
        const float* bc = xdbl + blo*(DTR + 2*DS) + DTR;   // B at [0..16), C at [16..32)
        float acc = 0.f;
        #pragma unroll
        for (int i = 0; i < 4; ++i) {
            const int s = sg*4 + i;
            h[i] = expf(dtv*A_[i])*h[i] + dtv*bc[s]*xv;
            acc += h[i]*bc[16 + s];
        }
        if (sg) part[sg-1][dil] = acc;
        __syncthreads();
        if (!sg) {
            float r = acc + part[0][dil] + part[1][dil] + part[2][dil] + Dpv*xv;
            const float zv = xz[blo*(2*DI) + DI + di];
            y[blo*DI + di] = r * (zv * sigmoidf_(zv));
        }
        __syncthreads();
    }
}

// ---------------- classification head ----------------
__global__ void head_kernel(const float* __restrict__ ln0, const float* __restrict__ hw,
                            const float* __restrict__ hb, float* __restrict__ out)
{
    const int idx = blockIdx.x*256 + threadIdx.x;
    if (idx >= B_*NCLS) return;
    const int n = idx % NCLS, b = idx / NCLS;
    const float* xr = ln0 + b*D_;
    const float* wr = hw + (long)n*D_;
    float acc = hb[n];
    #pragma unroll 4
    for (int k = 0; k < D_; ++k) acc += xr[k]*wr[k];
    out[idx] = acc;
}

extern "C" void kernel_launch(void* const* d_in, const int* in_sizes, int n_in,
                              void* d_out, int out_size, void* d_ws, size_t ws_size,
                              hipStream_t stream)
{
    const float* x       = (const float*)d_in[0];
    const float* patch_w = (const float*)d_in[1];
    const float* patch_b = (const float*)d_in[2];
    const float* cls_tok = (const float*)d_in[3];
    const float* pos_emb = (const float*)d_in[4];
    const float* ln_w    = (const float*)d_in[5];
    const float* ln_b    = (const float*)d_in[6];
    const float* in_w    = (const float*)d_in[7];
    const float* conv_w  = (const float*)d_in[8];
    const float* conv_b  = (const float*)d_in[9];
    const float* xp_w    = (const float*)d_in[10];
    const float* dt_w    = (const float*)d_in[11];
    const float* dt_b    = (const float*)d_in[12];
    const float* A_log   = (const float*)d_in[13];
    const float* D_par   = (const float*)d_in[14];
    const float* out_w   = (const float*)d_in[15];
    const float* normf_w = (const float*)d_in[16];
    const float* normf_b = (const float*)d_in[17];
    const float* head_w  = (const float*)d_in[18];
    const float* head_b  = (const float*)d_in[19];
    float* out = (float*)d_out;

    // workspace layout (floats); total ~27.0M floats ~= 108 MB
    float* ws    = (float*)d_ws;
    const long NT = NTOK;
    float* tok   = ws;                 // NT*384   residual stream
    float* xz    = tok  + NT*D_;       // NT*1536  in_proj out (xb | z)
    float* xbc   = xz   + NT*2*DI;     // NT*768   conv+silu out
    float* xdbl  = xbc  + NT*DI;       // NT*56    x_proj out (dt|B|C)
    float* dtbuf = xdbl + NT*(DTR+2*DS); // NT*768
    float* ybuf  = dtbuf + NT*DI;      // NT*768   (aliases xnorm: disjoint lifetimes)
    float* xnorm = ybuf;
    float* ln0   = ybuf + NT*DI;       // 32*384

    patch_embed_kernel<<<dim3(L_, B_), 384, 0, stream>>>(x, patch_w, patch_b, cls_tok, pos_emb, tok);

    for (int layer = 0; layer < DEPTH; ++layer) {
        ln_kernel<<<dim3(NTOK/4), dim3(64,4), 0, stream>>>(
            tok, ln_w + layer*D_, ln_b + layer*D_, xnorm, NTOK, D_, D_);
        gemm_nt_kernel<<<dim3(99, 24), 256, 0, stream>>>(
            xnorm, in_w + (long)layer*2*DI*D_, xz, NTOK, 2*DI, D_, 0);
        conv_silu_kernel<<<dim3((NTOK*DI + 255)/256), 256, 0, stream>>>(
            xz, conv_w + layer*DI*DCONV, conv_b + layer*DI, xbc);
        xproj_kernel<<<dim3(NTOK), 64, 0, stream>>>(
            xbc, xp_w + (long)layer*(DTR+2*DS)*DI, xdbl);
        dtproj_kernel<<<dim3((NTOK*DI + 255)/256), 256, 0, stream>>>(
            xdbl, dt_w + layer*DI*DTR, dt_b + layer*DI, dtbuf);
        scan_kernel<<<dim3(12, B_), 256, 0, stream>>>(
            dtbuf, xbc, xdbl, xz, A_log + layer*DI*DS, D_par + layer*DI, ybuf);
        gemm_nt_kernel<<<dim3(99, 6), 256, 0, stream>>>(
            ybuf, out_w + (long)layer*D_*DI, tok, NTOK, D_, DI, 1);
    }

    ln_kernel<<<dim3(8), dim3(64,4), 0, stream>>>(tok, normf_w, normf_b, ln0, B_, L_*D_, D_);
    head_kernel<<<dim3((B_*NCLS + 255)/256), 256, 0, stream>>>(ln0, head_w, head_b, out);
}

// Round 2
// 10974.158 us; speedup vs baseline: 1.5088x; 1.5088x over previous
//
#include <hip/hip_runtime.h>
#include <math.h>

// ---- problem dims ----
#define B_    32
#define D_    384
#define DEPTH 24
#define DI    768
#define DS    16
#define DCONV 4
#define DTR   24
#define L_    197
#define NCLS  1000
#define NTOK  (B_*L_)   // 6304
#define MPAD  6400      // 50*128, padded row count for GEMM A buffers

typedef __bf16 bf16;
typedef __bf16 bf16x8 __attribute__((ext_vector_type(8)));
typedef float  floatx4 __attribute__((ext_vector_type(4)));

__device__ __forceinline__ float sigmoidf_(float x){ return 1.f/(1.f+expf(-x)); }
__device__ __forceinline__ float softplusf_(float x){ return (x>20.f)? x : log1pf(expf(x)); }

// ---------------- patch embedding + cls + pos ----------------
__global__ void patch_embed_kernel(const float* __restrict__ x, const float* __restrict__ pw,
                                   const float* __restrict__ pb, const float* __restrict__ cls,
                                   const float* __restrict__ pos, float* __restrict__ tok)
{
    __shared__ float patch[768];
    const int p = blockIdx.x;          // 0..196, 0 = cls token
    const int b = blockIdx.y;
    const int t = threadIdx.x;         // 0..383 = output channel d
    if (p == 0) {
        tok[((long)b*L_)*D_ + t] = cls[t] + pos[t];
        return;
    }
    const int pi = p - 1, ph = pi/14, pwc = pi%14;
    for (int i = t; i < 768; i += 384) {
        int c = i >> 8, rem = i & 255, ii = rem >> 4, jj = rem & 15;
        patch[i] = x[(((long)b*3 + c)*224 + (ph*16 + ii))*224 + pwc*16 + jj];
    }
    __syncthreads();
    float acc = pb[t];
    const float* wr = pw + (long)t*768;
    #pragma unroll 4
    for (int k = 0; k < 768; ++k) acc += patch[k]*wr[k];
    tok[((long)b*L_ + p)*D_ + t] = acc + pos[p*D_ + t];
}

// ---------------- layernorm over last dim 384, one wave per row ----------------
template<typename OUT_T>
__global__ void ln_kernel(const float* __restrict__ x, const float* __restrict__ w,
                          const float* __restrict__ b, OUT_T* __restrict__ out,
                          int rows, int xstride, int ostride)
{
    const int row = blockIdx.x*blockDim.y + threadIdx.y;
    if (row >= rows) return;
    const int lane = threadIdx.x;
    const float* xr = x + (long)row*xstride;
    float v[6]; float s = 0.f;
    #pragma unroll
    for (int i = 0; i < 6; ++i) { v[i] = xr[lane + 64*i]; s += v[i]; }
    #pragma unroll
    for (int o = 32; o; o >>= 1) s += __shfl_xor(s, o, 64);
    const float mu = s * (1.f/384.f);
    float var = 0.f;
    #pragma unroll
    for (int i = 0; i < 6; ++i) { float d = v[i]-mu; var += d*d; }
    #pragma unroll
    for (int o = 32; o; o >>= 1) var += __shfl_xor(var, o, 64);
    const float rstd = rsqrtf(var*(1.f/384.f) + 1e-5f);
    OUT_T* orow = out + (long)row*ostride;
    #pragma unroll
    for (int i = 0; i < 6; ++i) { int c = lane + 64*i; orow[c] = (OUT_T)((v[i]-mu)*rstd*w[c] + b[c]); }
}

// ---------------- bf16 MFMA GEMM:  C[m,n] (+)= A[m,:K] . B[n,:K]  (B stored [N][K]) ----------------
// 128x128 tile, BK=32, 256 threads (4 waves 2x2 of 64x64), global_load_lds staging.
template<int ACC>
__global__ __launch_bounds__(256)
void gemm_bf16_kernel(const bf16* __restrict__ A, const bf16* __restrict__ B,
                      float* __restrict__ C, int M, int N, int K)
{
    __shared__ bf16 As[128*32];
    __shared__ bf16 Bs[128*32];
    const int tid  = threadIdx.x;
    const int wave = tid >> 6, lane = tid & 63;
    const int bm = blockIdx.x*128, bn = blockIdx.y*128;
    const int wm = (wave>>1)*64, wn = (wave&1)*64;
    floatx4 acc[4][4];
    #pragma unroll
    for (int i=0;i<4;++i)
        #pragma unroll
        for (int j=0;j<4;++j) acc[i][j] = (floatx4){0.f,0.f,0.f,0.f};

    const int lrow = lane >> 2;          // 0..15  (row within 16-row slab)
    const int lcol = (lane & 3) * 8;     // bf16 element col offset (0/8/16/24)
    const int am = lane & 15, ak = (lane>>4)*8;

    for (int k0 = 0; k0 < K; k0 += 32) {
        #pragma unroll
        for (int it = 0; it < 2; ++it) {
            const int slab = wave*2 + it;          // 0..7, 16 rows each
            const int r = slab*16 + lrow;
            const bf16* ga = A + (long)(bm + r)*K + k0 + lcol;
            const bf16* gb = B + (long)(bn + r)*K + k0 + lcol;
            __builtin_amdgcn_global_load_lds(
                (const __attribute__((address_space(1))) void*)ga,
                (__attribute__((address_space(3))) void*)(As + slab*512), 16, 0, 0);
            __builtin_amdgcn_global_load_lds(
                (const __attribute__((address_space(1))) void*)gb,
                (__attribute__((address_space(3))) void*)(Bs + slab*512), 16, 0, 0);
        }
        __syncthreads();
        bf16x8 af[4], bff[4];
        #pragma unroll
        for (int i=0;i<4;++i) af[i]  = *(const bf16x8*)(As + (wm + i*16 + am)*32 + ak);
        #pragma unroll
        for (int j=0;j<4;++j) bff[j] = *(const bf16x8*)(Bs + (wn + j*16 + am)*32 + ak);
        #pragma unroll
        for (int i=0;i<4;++i)
            #pragma unroll
            for (int j=0;j<4;++j)
                acc[i][j] = __builtin_amdgcn_mfma_f32_16x16x32_bf16(af[i], bff[j], acc[i][j], 0, 0, 0);
        __syncthreads();
    }
    // epilogue: C/D layout col=lane&15, row=(lane>>4)*4+reg
    const int rbase = bm + wm + (lane>>4)*4;
    const int cbase = bn + wn + (lane & 15);
    #pragma unroll
    for (int i = 0; i < 4; ++i) {
        #pragma unroll
        for (int r = 0; r < 4; ++r) {
            const int row = rbase + i*16 + r;
            if (row >= M) continue;
            #pragma unroll
            for (int j = 0; j < 4; ++j) {
                const long idx = (long)row*N + cbase + j*16;
                if (ACC) C[idx] += acc[i][j][r];
                else     C[idx]  = acc[i][j][r];
            }
        }
    }
}

// ---------------- per-layer weight -> bf16 conversion (in_w, out_w, xp_w padded) ----------------
#define INW_E  (1536*384)
#define OUTW_E (384*768)
#define XPW_E  (128*768)
__global__ void wconv_kernel(const float* __restrict__ in_w, const float* __restrict__ out_w,
                             const float* __restrict__ xp_w,
                             bf16* __restrict__ w_in_b, bf16* __restrict__ w_out_b,
                             bf16* __restrict__ w_xp_b)
{
    int idx = blockIdx.x*256 + threadIdx.x;
    if (idx < INW_E) { w_in_b[idx] = (bf16)in_w[idx]; return; }
    idx -= INW_E;
    if (idx < OUTW_E) { w_out_b[idx] = (bf16)out_w[idx]; return; }
    idx -= OUTW_E;
    if (idx < XPW_E) w_xp_b[idx] = (idx < 56*768) ? (bf16)xp_w[idx] : (bf16)0.f;
}

// ---------------- causal depthwise conv1d (DCONV=4) + bias + silu -> bf16 ----------------
__global__ void conv_silu_kernel(const float* __restrict__ xz, const float* __restrict__ cw,
                                 const float* __restrict__ cb, bf16* __restrict__ out)
{
    const int idx = blockIdx.x*256 + threadIdx.x;      // (b*L + l)*DI + di
    if (idx >= NTOK*DI) return;
    const int di = idx % DI;
    const int bl = idx / DI;
    const int l  = bl % L_;
    const long rowbase = (long)(bl - l) * (2*DI) + di;
    const float w0 = cw[di*4], w1 = cw[di*4+1], w2 = cw[di*4+2], w3 = cw[di*4+3];
    float acc = cb[di];
    if (l >= 3) acc += w0 * xz[rowbase + (long)(l-3)*(2*DI)];
    if (l >= 2) acc += w1 * xz[rowbase + (long)(l-2)*(2*DI)];
    if (l >= 1) acc += w2 * xz[rowbase + (long)(l-1)*(2*DI)];
    acc += w3 * xz[rowbase + (long)l*(2*DI)];
    out[idx] = (bf16)(acc * sigmoidf_(acc));
}

// ---------------- fused dt_proj + selective scan + D-skip + gate -> y bf16 ----------------
// block = 1 wave: lanes 0-31 di-group states 0-7, lanes 32-63 same di states 8-15.
// grid (DI/32, B_). xdbl has row stride 128 (dt 0:24 | B 24:40 | C 40:56).
__global__ __launch_bounds__(64)
void scan_kernel(const bf16* __restrict__ xbc, const float* __restrict__ xdbl,
                 const float* __restrict__ xz, const float* __restrict__ A_log,
                 const float* __restrict__ Dp, const float* __restrict__ dtw,
                 const float* __restrict__ dtb, bf16* __restrict__ y)
{
    const int lane = threadIdx.x;
    const int half = lane >> 5;
    const int di   = blockIdx.x*32 + (lane & 31);
    const int b    = blockIdx.y;
    float A_[8], h[8];
    #pragma unroll
    for (int i = 0; i < 8; ++i) { A_[i] = -expf(A_log[di*DS + half*8 + i]); h[i] = 0.f; }
    float wdt[24];
    #pragma unroll
    for (int r = 0; r < 24; ++r) wdt[r] = dtw[di*DTR + r];
    const float bias = dtb[di], Dv = Dp[di];
    __shared__ float sh[8*64];   // up to 8 token rows of 56 (stride 64)

    for (int l0 = 0; l0 < L_; l0 += 8) {
        const int CH = (L_ - l0 < 8) ? (L_ - l0) : 8;
        const long blo0 = (long)b*L_ + l0;
        // stage xdbl rows into LDS (coalesced)
        for (int q = lane; q < CH*56; q += 64) {
            const int t = q/56, e = q - t*56;
            sh[t*64 + e] = xdbl[(blo0 + t)*128 + e];
        }
        // per-lane chunk loads
        float xv[8], zv[8];
        #pragma unroll
        for (int t = 0; t < 8; ++t) {
            if (t < CH) {
                xv[t] = (float)xbc[(blo0 + t)*DI + di];
                zv[t] = xz[(blo0 + t)*(2*DI) + DI + di];
            } else { xv[t] = 0.f; zv[t] = 0.f; }
        }
        __syncthreads();
        for (int t = 0; t < CH; ++t) {
            const float* row = sh + t*64;
            float dtacc = bias;
            #pragma unroll
            for (int r = 0; r < 24; ++r) dtacc += row[r]*wdt[r];
            const float dt = softplusf_(dtacc);
            float accv = 0.f;
            const float dx = dt * xv[t];
            #pragma unroll
            for (int i = 0; i < 8; ++i) {
                h[i] = expf(dt*A_[i])*h[i] + row[24 + half*8 + i]*dx;
                accv += h[i]*row[40 + half*8 + i];
            }
            const float tot = accv + __shfl_xor(accv, 32, 64);
            if (!half) {
                const float r2 = tot + Dv*xv[t];
                const float z  = zv[t];
                y[(blo0 + t)*DI + di] = (bf16)(r2 * z * sigmoidf_(z));
            }
        }
        __syncthreads();
    }
}

// ---------------- classification head ----------------
__global__ void head_kernel(const float* __restrict__ ln0, const float* __restrict__ hw,
                            const float* __restrict__ hb, float* __restrict__ out)
{
    const int idx = blockIdx.x*256 + threadIdx.x;
    if (idx >= B_*NCLS) return;
    const int n = idx % NCLS, b = idx / NCLS;
    const float* xr = ln0 + b*D_;
    const float* wr = hw + (long)n*D_;
    float acc = hb[n];
    #pragma unroll 4
    for (int k = 0; k < D_; ++k) acc += xr[k]*wr[k];
    out[idx] = acc;
}

extern "C" void kernel_launch(void* const* d_in, const int* in_sizes, int n_in,
                              void* d_out, int out_size, void* d_ws, size_t ws_size,
                              hipStream_t stream)
{
    const float* x       = (const float*)d_in[0];
    const float* patch_w = (const float*)d_in[1];
    const float* patch_b = (const float*)d_in[2];
    const float* cls_tok = (const float*)d_in[3];
    const float* pos_emb = (const float*)d_in[4];
    const float* ln_w    = (const float*)d_in[5];
    const float* ln_b    = (const float*)d_in[6];
    const float* in_w    = (const float*)d_in[7];
    const float* conv_w  = (const float*)d_in[8];
    const float* conv_b  = (const float*)d_in[9];
    const float* xp_w    = (const float*)d_in[10];
    const float* dt_w    = (const float*)d_in[11];
    const float* dt_b    = (const float*)d_in[12];
    const float* A_log   = (const float*)d_in[13];
    const float* D_par   = (const float*)d_in[14];
    const float* out_w   = (const float*)d_in[15];
    const float* normf_w = (const float*)d_in[16];
    const float* normf_b = (const float*)d_in[17];
    const float* head_w  = (const float*)d_in[18];
    const float* head_b  = (const float*)d_in[19];
    float* out = (float*)d_out;

    // workspace layout (~78 MB)
    char* p = (char*)d_ws;
    float* tok   = (float*)p;            p += (long)NTOK*D_*4;        // 9.68 MB
    float* xz    = (float*)p;            p += (long)NTOK*2*DI*4;      // 38.7 MB
    float* xdbl  = (float*)p;            p += (long)NTOK*128*4;       // 3.23 MB
    float* ln0   = (float*)p;            p += (long)B_*D_*4;
    bf16* xnorm_b = (bf16*)p;            p += (long)MPAD*D_*2;        // 4.92 MB
    bf16* xbc_b   = (bf16*)p;            p += (long)MPAD*DI*2;        // 9.83 MB
    bf16* y_b     = (bf16*)p;            p += (long)MPAD*DI*2;        // 9.83 MB
    bf16* w_in_b  = (bf16*)p;            p += (long)INW_E*2;
    bf16* w_out_b = (bf16*)p;            p += (long)OUTW_E*2;
    bf16* w_xp_b  = (bf16*)p;            p += (long)XPW_E*2;

    patch_embed_kernel<<<dim3(L_, B_), 384, 0, stream>>>(x, patch_w, patch_b, cls_tok, pos_emb, tok);

    const int WCONV_BLOCKS = (INW_E + OUTW_E + XPW_E + 255)/256;
    for (int layer = 0; layer < DEPTH; ++layer) {
        wconv_kernel<<<WCONV_BLOCKS, 256, 0, stream>>>(
            in_w + (long)layer*INW_E, out_w + (long)layer*OUTW_E, xp_w + (long)layer*56*768,
            w_in_b, w_out_b, w_xp_b);
        ln_kernel<bf16><<<dim3(NTOK/4), dim3(64,4), 0, stream>>>(
            tok, ln_w + layer*D_, ln_b + layer*D_, xnorm_b, NTOK, D_, D_);
        gemm_bf16_kernel<0><<<dim3(50, 12), 256, 0, stream>>>(
            xnorm_b, w_in_b, xz, NTOK, 2*DI, D_);
        conv_silu_kernel<<<dim3((NTOK*DI + 255)/256), 256, 0, stream>>>(
            xz, conv_w + layer*DI*DCONV, conv_b + layer*DI, xbc_b);
        gemm_bf16_kernel<0><<<dim3(50, 1), 256, 0, stream>>>(
            xbc_b, w_xp_b, xdbl, NTOK, 128, DI);
        scan_kernel<<<dim3(DI/32, B_), 64, 0, stream>>>(
            xbc_b, xdbl, xz, A_log + layer*DI*DS, D_par + layer*DI,
            dt_w + layer*DI*DTR, dt_b + layer*DI, y_b);
        gemm_bf16_kernel<1><<<dim3(50, 3), 256, 0, stream>>>(
            y_b, w_out_b, tok, NTOK, D_, DI);
    }

    ln_kernel<float><<<dim3(8), dim3(64,4), 0, stream>>>(tok, normf_w, normf_b, ln0, B_, L_*D_, D_);
    head_kernel<<<dim3((B_*NCLS + 255)/256), 256, 0, stream>>>(ln0, head_w, head_b, out);
}

// Round 3
// 8429.395 us; speedup vs baseline: 1.9643x; 1.3019x over previous
//
#include <hip/hip_runtime.h>
#include <math.h>

// ---- problem dims ----
#define B_    32
#define D_    384
#define DEPTH 24
#define DI    768
#define DS    16
#define DCONV 4
#define DTR   24
#define L_    197
#define NCLS  1000
#define NTOK  (B_*L_)   // 6304
#define MPAD  6400      // padded row count for GEMM A buffers

typedef __bf16 bf16;
typedef __bf16 bf16x8 __attribute__((ext_vector_type(8)));
typedef float  floatx4 __attribute__((ext_vector_type(4)));

#define INW_E  (1536*384)
#define OUTW_E (384*768)
#define XPW_E  (128*768)
#define PW_E   (384*768)
#define HW_E   (1024*384)

__device__ __forceinline__ float sigmoidf_(float x){ return 1.f/(1.f+expf(-x)); }
__device__ __forceinline__ float softplusf_(float x){ return (x>20.f)? x : log1pf(expf(x)); }

// ---------------- all-weights fp32 -> bf16 conversion (once per call) ----------------
__global__ void wconv_all_kernel(const float* __restrict__ in_w, const float* __restrict__ out_w,
                                 const float* __restrict__ xp_w, const float* __restrict__ patch_w,
                                 const float* __restrict__ head_w,
                                 bf16* __restrict__ w_in_b, bf16* __restrict__ w_out_b,
                                 bf16* __restrict__ w_xp_b, bf16* __restrict__ pw_b,
                                 bf16* __restrict__ hw_b)
{
    long idx = (long)blockIdx.x*256 + threadIdx.x;
    if (idx < (long)DEPTH*INW_E) { w_in_b[idx] = (bf16)in_w[idx]; return; }
    idx -= (long)DEPTH*INW_E;
    if (idx < (long)DEPTH*OUTW_E) { w_out_b[idx] = (bf16)out_w[idx]; return; }
    idx -= (long)DEPTH*OUTW_E;
    if (idx < (long)DEPTH*XPW_E) {
        const int l = idx / XPW_E, loc = idx % XPW_E;
        w_xp_b[idx] = (loc < 56*768) ? (bf16)xp_w[(long)l*56*768 + loc] : (bf16)0.f;
        return;
    }
    idx -= (long)DEPTH*XPW_E;
    if (idx < PW_E) { pw_b[idx] = (bf16)patch_w[idx]; return; }
    idx -= PW_E;
    if (idx < HW_E) hw_b[idx] = (idx < (long)NCLS*384) ? (bf16)head_w[idx] : (bf16)0.f;
}

// ---------------- im2col: x[B,3,224,224] -> patches[b*197+1+pi, 768] bf16 ----------------
__global__ void im2col_kernel(const float* __restrict__ x, bf16* __restrict__ patches)
{
    const long idx = (long)blockIdx.x*256 + threadIdx.x;
    if (idx >= (long)B_*196*768) return;
    const int k = idx % 768;
    const int prow = idx / 768;
    const int b = prow / 196, pi = prow % 196;
    const int ph = pi / 14, pw = pi % 14;
    const int c = k >> 8, rem = k & 255, ii = rem >> 4, jj = rem & 15;
    patches[((long)(b*L_ + 1 + pi))*768 + k] =
        (bf16)x[(((long)b*3 + c)*224 + ph*16 + ii)*224 + pw*16 + jj];
}

// ---------------- tok = feat + pb + pos ; cls row = cls + pos ----------------
__global__ void add_pos_kernel(float* __restrict__ tok, const float* __restrict__ pb,
                               const float* __restrict__ pos, const float* __restrict__ cls)
{
    const int idx = blockIdx.x*256 + threadIdx.x;
    if (idx >= NTOK*D_) return;
    const int dd = idx % D_;
    const int row = idx / D_;
    const int p = row % L_;
    if (p == 0) tok[idx] = cls[dd] + pos[dd];
    else        tok[idx] += pb[dd] + pos[p*D_ + dd];
}

// ---------------- layernorm over last dim 384, one wave per row ----------------
template<typename OUT_T>
__global__ void ln_kernel(const float* __restrict__ x, const float* __restrict__ w,
                          const float* __restrict__ b, OUT_T* __restrict__ out,
                          int rows, int xstride, int ostride)
{
    const int row = blockIdx.x*blockDim.y + threadIdx.y;
    if (row >= rows) return;
    const int lane = threadIdx.x;
    const float* xr = x + (long)row*xstride;
    float v[6]; float s = 0.f;
    #pragma unroll
    for (int i = 0; i < 6; ++i) { v[i] = xr[lane + 64*i]; s += v[i]; }
    #pragma unroll
    for (int o = 32; o; o >>= 1) s += __shfl_xor(s, o, 64);
    const float mu = s * (1.f/384.f);
    float var = 0.f;
    #pragma unroll
    for (int i = 0; i < 6; ++i) { float d = v[i]-mu; var += d*d; }
    #pragma unroll
    for (int o = 32; o; o >>= 1) var += __shfl_xor(var, o, 64);
    const float rstd = rsqrtf(var*(1.f/384.f) + 1e-5f);
    OUT_T* orow = out + (long)row*ostride;
    #pragma unroll
    for (int i = 0; i < 6; ++i) { int c = lane + 64*i; orow[c] = (OUT_T)((v[i]-mu)*rstd*w[c] + b[c]); }
}

// ---------------- bf16 MFMA GEMM:  C[m,n] (+)= A[m,:K] . B[n,:K]  (B stored [N][K]) ----------------
// BMx128 tile, BK=32, 256 threads.  BM=128: 4 waves 2x2 of 64x64.  BM=64: 4 waves of 64x32.
template<int BM, int ACC, typename CT>
__global__ __launch_bounds__(256)
void gemm_bf16_kernel(const bf16* __restrict__ A, const bf16* __restrict__ B,
                      CT* __restrict__ C, int M, int N, int K)
{
    constexpr int ASLABS = BM/16;
    constexpr int NJ = (BM == 128) ? 4 : 2;
    __shared__ bf16 As[BM*32];
    __shared__ bf16 Bs[128*32];
    const int tid  = threadIdx.x;
    const int wave = tid >> 6, lane = tid & 63;
    const int bm = blockIdx.x*BM, bn = blockIdx.y*128;
    const int wm = (BM == 128) ? (wave>>1)*64 : 0;
    const int wn = (BM == 128) ? (wave&1)*64 : wave*32;
    floatx4 acc[4][NJ];
    #pragma unroll
    for (int i=0;i<4;++i)
        #pragma unroll
        for (int j=0;j<NJ;++j) acc[i][j] = (floatx4){0.f,0.f,0.f,0.f};

    const int lrow = lane >> 2;          // 0..15 (row within 16-row slab)
    const int lcol = (lane & 3) * 8;     // bf16 element col offset
    const int am = lane & 15, ak = (lane>>4)*8;

    for (int k0 = 0; k0 < K; k0 += 32) {
        #pragma unroll
        for (int s = wave; s < ASLABS + 8; s += 4) {
            if (s < ASLABS) {
                const bf16* ga = A + (long)(bm + s*16 + lrow)*K + k0 + lcol;
                __builtin_amdgcn_global_load_lds(
                    (const __attribute__((address_space(1))) void*)ga,
                    (__attribute__((address_space(3))) void*)(As + s*512), 16, 0, 0);
            } else {
                const int s2 = s - ASLABS;
                const bf16* gb = B + (long)(bn + s2*16 + lrow)*K + k0 + lcol;
                __builtin_amdgcn_global_load_lds(
                    (const __attribute__((address_space(1))) void*)gb,
                    (__attribute__((address_space(3))) void*)(Bs + s2*512), 16, 0, 0);
            }
        }
        __syncthreads();
        bf16x8 af[4], bff[NJ];
        #pragma unroll
        for (int i=0;i<4;++i) af[i]  = *(const bf16x8*)(As + (wm + i*16 + am)*32 + ak);
        #pragma unroll
        for (int j=0;j<NJ;++j) bff[j] = *(const bf16x8*)(Bs + (wn + j*16 + am)*32 + ak);
        #pragma unroll
        for (int i=0;i<4;++i)
            #pragma unroll
            for (int j=0;j<NJ;++j)
                acc[i][j] = __builtin_amdgcn_mfma_f32_16x16x32_bf16(af[i], bff[j], acc[i][j], 0, 0, 0);
        __syncthreads();
    }
    // epilogue: C/D layout col=lane&15, row=(lane>>4)*4+reg
    const int rbase = bm + wm + (lane>>4)*4;
    const int cbase = bn + wn + (lane & 15);
    #pragma unroll
    for (int i = 0; i < 4; ++i) {
        #pragma unroll
        for (int r = 0; r < 4; ++r) {
            const int row = rbase + i*16 + r;
            if (row >= M) continue;
            #pragma unroll
            for (int j = 0; j < NJ; ++j) {
                const long idx = (long)row*N + cbase + j*16;
                if (ACC) C[idx] += acc[i][j][r];
                else     C[idx]  = (CT)acc[i][j][r];
            }
        }
    }
}

// ---------------- causal depthwise conv1d (DCONV=4) + bias + silu -> bf16 ----------------
__global__ void conv_silu_kernel(const bf16* __restrict__ xz, const float* __restrict__ cw,
                                 const float* __restrict__ cb, bf16* __restrict__ out)
{
    const int idx = blockIdx.x*256 + threadIdx.x;      // (b*L + l)*DI + di
    if (idx >= NTOK*DI) return;
    const int di = idx % DI;
    const int bl = idx / DI;
    const int l  = bl % L_;
    const long rowbase = (long)(bl - l) * (2*DI) + di;
    const float w0 = cw[di*4], w1 = cw[di*4+1], w2 = cw[di*4+2], w3 = cw[di*4+3];
    float acc = cb[di];
    if (l >= 3) acc += w0 * (float)xz[rowbase + (long)(l-3)*(2*DI)];
    if (l >= 2) acc += w1 * (float)xz[rowbase + (long)(l-2)*(2*DI)];
    if (l >= 1) acc += w2 * (float)xz[rowbase + (long)(l-1)*(2*DI)];
    acc += w3 * (float)xz[rowbase + (long)l*(2*DI)];
    out[idx] = (bf16)(acc * sigmoidf_(acc));
}

// ---------------- fused dt_proj + selective scan + D-skip + gate -> y bf16 ----------------
// block 256 = 4 waves; wave covers 16 di, 4 lanes (q) per di with 4 states each.
// grid (DI/64, B_). xdbl row stride 128 (dt 0:24 | B 24:40 | C 40:56).
__global__ __launch_bounds__(256)
void scan_kernel(const bf16* __restrict__ xbc, const float* __restrict__ xdbl,
                 const bf16* __restrict__ xz, const float* __restrict__ A_log,
                 const float* __restrict__ Dp, const float* __restrict__ dtw,
                 const float* __restrict__ dtb, bf16* __restrict__ y)
{
    const int tid  = threadIdx.x;
    const int wave = tid >> 6, lane = tid & 63;
    const int q = lane >> 4, d = lane & 15;
    const int di = blockIdx.x*64 + wave*16 + d;
    const int b  = blockIdx.y;
    float A_[4], h[4] = {0.f, 0.f, 0.f, 0.f};
    #pragma unroll
    for (int i = 0; i < 4; ++i) A_[i] = -expf(A_log[di*DS + q*4 + i]);
    float wdt6[6];
    #pragma unroll
    for (int r = 0; r < 6; ++r) wdt6[r] = dtw[di*DTR + q*6 + r];
    const float bias = dtb[di], Dv = Dp[di];
    __shared__ float sh[8*64];

    for (int l0 = 0; l0 < L_; l0 += 8) {
        const int CH = (L_ - l0 < 8) ? (L_ - l0) : 8;
        const long blo0 = (long)b*L_ + l0;
        __syncthreads();
        for (int idx = tid; idx < CH*56; idx += 256) {
            const int t = idx/56, e = idx - t*56;
            sh[t*64 + e] = xdbl[(blo0 + t)*128 + e];
        }
        float xv[8], zv[8];
        #pragma unroll
        for (int t = 0; t < 8; ++t) {
            if (t < CH) {
                xv[t] = (float)xbc[(blo0 + t)*DI + di];
                zv[t] = (q == 0) ? (float)xz[(blo0 + t)*(2*DI) + DI + di] : 0.f;
            } else { xv[t] = 0.f; zv[t] = 0.f; }
        }
        __syncthreads();
        for (int t = 0; t < CH; ++t) {
            const float* row = sh + t*64;
            float p = 0.f;
            #pragma unroll
            for (int r = 0; r < 6; ++r) p += row[q*6 + r]*wdt6[r];
            p += __shfl_xor(p, 16, 64);
            p += __shfl_xor(p, 32, 64);
            const float dtv = softplusf_(bias + p);
            const float dx = dtv * xv[t];
            float acc = 0.f;
            #pragma unroll
            for (int i = 0; i < 4; ++i) {
                h[i] = expf(dtv*A_[i])*h[i] + row[24 + q*4 + i]*dx;
                acc += h[i]*row[40 + q*4 + i];
            }
            acc += __shfl_xor(acc, 16, 64);
            acc += __shfl_xor(acc, 32, 64);
            if (q == 0) {
                const float r2 = acc + Dv*xv[t];
                const float z  = zv[t];
                y[(blo0 + t)*DI + di] = (bf16)(r2 * z * sigmoidf_(z));
            }
        }
    }
}

// ---------------- head bias + copy from padded GEMM output ----------------
__global__ void head_bias_kernel(const float* __restrict__ chead, const float* __restrict__ hb,
                                 float* __restrict__ out)
{
    const int idx = blockIdx.x*256 + threadIdx.x;
    if (idx >= B_*NCLS) return;
    const int n = idx % NCLS, b = idx / NCLS;
    out[idx] = chead[(long)b*1024 + n] + hb[n];
}

extern "C" void kernel_launch(void* const* d_in, const int* in_sizes, int n_in,
                              void* d_out, int out_size, void* d_ws, size_t ws_size,
                              hipStream_t stream)
{
    const float* x       = (const float*)d_in[0];
    const float* patch_w = (const float*)d_in[1];
    const float* patch_b = (const float*)d_in[2];
    const float* cls_tok = (const float*)d_in[3];
    const float* pos_emb = (const float*)d_in[4];
    const float* ln_w    = (const float*)d_in[5];
    const float* ln_b    = (const float*)d_in[6];
    const float* in_w    = (const float*)d_in[7];
    const float* conv_w  = (const float*)d_in[8];
    const float* conv_b  = (const float*)d_in[9];
    const float* xp_w    = (const float*)d_in[10];
    const float* dt_w    = (const float*)d_in[11];
    const float* dt_b    = (const float*)d_in[12];
    const float* A_log   = (const float*)d_in[13];
    const float* D_par   = (const float*)d_in[14];
    const float* out_w   = (const float*)d_in[15];
    const float* normf_w = (const float*)d_in[16];
    const float* normf_b = (const float*)d_in[17];
    const float* head_w  = (const float*)d_in[18];
    const float* head_b  = (const float*)d_in[19];
    float* out = (float*)d_out;

    // workspace layout (~106 MB)
    char* p = (char*)d_ws;
    float* tok    = (float*)p;  p += (long)NTOK*D_*4;          // 9.68 MB
    bf16*  xz_b   = (bf16*)p;   p += (long)MPAD*2*DI*2;        // 19.66 MB
    bf16*  xbc_b  = (bf16*)p;   p += (long)MPAD*DI*2;          // 9.83 MB
    bf16*  y_b    = (bf16*)p;   p += (long)MPAD*DI*2;          // 9.83 MB (aliased: im2col patches)
    float* xdbl   = (float*)p;  p += (long)MPAD*128*4;         // 3.28 MB
    bf16*  xnorm_b= (bf16*)p;   p += (long)MPAD*D_*2;          // 4.92 MB
    bf16*  ln0_b  = (bf16*)p;   p += (long)64*D_*2;
    float* chead  = (float*)p;  p += (long)64*1024*4;
    bf16*  w_in_b = (bf16*)p;   p += (long)DEPTH*INW_E*2;      // 28.3 MB
    bf16*  w_out_b= (bf16*)p;   p += (long)DEPTH*OUTW_E*2;     // 14.2 MB
    bf16*  w_xp_b = (bf16*)p;   p += (long)DEPTH*XPW_E*2;      // 4.72 MB
    bf16*  pw_b   = (bf16*)p;   p += (long)PW_E*2;             // 0.59 MB
    bf16*  hw_b   = (bf16*)p;   p += (long)HW_E*2;             // 0.79 MB
    bf16*  patches = y_b;

    const long WCONV_E = (long)DEPTH*(INW_E + OUTW_E + XPW_E) + PW_E + HW_E;
    wconv_all_kernel<<<dim3((WCONV_E + 255)/256), 256, 0, stream>>>(
        in_w, out_w, xp_w, patch_w, head_w, w_in_b, w_out_b, w_xp_b, pw_b, hw_b);

    im2col_kernel<<<dim3(((long)B_*196*768 + 255)/256), 256, 0, stream>>>(x, patches);
    gemm_bf16_kernel<64,0,float><<<dim3(100, 3), 256, 0, stream>>>(
        patches, pw_b, tok, NTOK, D_, 768);
    add_pos_kernel<<<dim3((NTOK*D_ + 255)/256), 256, 0, stream>>>(tok, patch_b, pos_emb, cls_tok);

    for (int layer = 0; layer < DEPTH; ++layer) {
        ln_kernel<bf16><<<dim3(NTOK/4), dim3(64,4), 0, stream>>>(
            tok, ln_w + layer*D_, ln_b + layer*D_, xnorm_b, NTOK, D_, D_);
        gemm_bf16_kernel<128,0,bf16><<<dim3(50, 12), 256, 0, stream>>>(
            xnorm_b, w_in_b + (long)layer*INW_E, xz_b, NTOK, 2*DI, D_);
        conv_silu_kernel<<<dim3((NTOK*DI + 255)/256), 256, 0, stream>>>(
            xz_b, conv_w + layer*DI*DCONV, conv_b + layer*DI, xbc_b);
        gemm_bf16_kernel<64,0,float><<<dim3(100, 1), 256, 0, stream>>>(
            xbc_b, w_xp_b + (long)layer*XPW_E, xdbl, NTOK, 128, DI);
        scan_kernel<<<dim3(DI/64, B_), 256, 0, stream>>>(
            xbc_b, xdbl, xz_b, A_log + layer*DI*DS, D_par + layer*DI,
            dt_w + layer*DI*DTR, dt_b + layer*DI, y_b);
        gemm_bf16_kernel<64,1,float><<<dim3(100, 3), 256, 0, stream>>>(
            y_b, w_out_b + (long)layer*OUTW_E, tok, NTOK, D_, DI);
    }

    ln_kernel<bf16><<<dim3(8), dim3(64,4), 0, stream>>>(tok, normf_w, normf_b, ln0_b, B_, L_*D_, D_);
    gemm_bf16_kernel<64,0,float><<<dim3(1, 8), 256, 0, stream>>>(
        ln0_b, hw_b, chead, 64, 1024, D_);
    head_bias_kernel<<<dim3((B_*NCLS + 255)/256), 256, 0, stream>>>(chead, head_b, out);
}

// Round 4
// 6786.171 us; speedup vs baseline: 2.4399x; 1.2421x over previous
//
#include <hip/hip_runtime.h>
#include <math.h>

// ---- problem dims ----
#define B_    32
#define D_    384
#define DEPTH 24
#define DI    768
#define DS    16
#define DCONV 4
#define DTR   24
#define L_    197
#define NCLS  1000
#define NTOK  (B_*L_)   // 6304
#define MPAD  6400      // padded row count for GEMM A buffers

typedef __bf16 bf16;
typedef __bf16 bf16x2 __attribute__((ext_vector_type(2)));
typedef __bf16 bf16x8 __attribute__((ext_vector_type(8)));
typedef float  floatx4 __attribute__((ext_vector_type(4)));

#define INW_E  (1536*384)
#define OUTW_E (384*768)
#define XPW_E  (128*768)
#define PW_E   (384*768)
#define HW_E   (1024*384)

__device__ __forceinline__ float sigmoidf_(float x){ return 1.f/(1.f+__expf(-x)); }

// ---------------- all-weights fp32 -> bf16 conversion (once per call) ----------------
__global__ void wconv_all_kernel(const float* __restrict__ in_w, const float* __restrict__ out_w,
                                 const float* __restrict__ xp_w, const float* __restrict__ patch_w,
                                 const float* __restrict__ head_w,
                                 bf16* __restrict__ w_in_b, bf16* __restrict__ w_out_b,
                                 bf16* __restrict__ w_xp_b, bf16* __restrict__ pw_b,
                                 bf16* __restrict__ hw_b)
{
    long idx = (long)blockIdx.x*256 + threadIdx.x;
    if (idx < (long)DEPTH*INW_E) { w_in_b[idx] = (bf16)in_w[idx]; return; }
    idx -= (long)DEPTH*INW_E;
    if (idx < (long)DEPTH*OUTW_E) { w_out_b[idx] = (bf16)out_w[idx]; return; }
    idx -= (long)DEPTH*OUTW_E;
    if (idx < (long)DEPTH*XPW_E) {
        const int l = idx / XPW_E, loc = idx % XPW_E;
        w_xp_b[idx] = (loc < 56*768) ? (bf16)xp_w[(long)l*56*768 + loc] : (bf16)0.f;
        return;
    }
    idx -= (long)DEPTH*XPW_E;
    if (idx < PW_E) { pw_b[idx] = (bf16)patch_w[idx]; return; }
    idx -= PW_E;
    if (idx < HW_E) hw_b[idx] = (idx < (long)NCLS*384) ? (bf16)head_w[idx] : (bf16)0.f;
}

// ---------------- im2col: x[B,3,224,224] -> patches[b*197+1+pi, 768] bf16 ----------------
__global__ void im2col_kernel(const float* __restrict__ x, bf16* __restrict__ patches)
{
    const long idx = (long)blockIdx.x*256 + threadIdx.x;
    if (idx >= (long)B_*196*768) return;
    const int k = idx % 768;
    const int prow = idx / 768;
    const int b = prow / 196, pi = prow % 196;
    const int ph = pi / 14, pw = pi % 14;
    const int c = k >> 8, rem = k & 255, ii = rem >> 4, jj = rem & 15;
    patches[((long)(b*L_ + 1 + pi))*768 + k] =
        (bf16)x[(((long)b*3 + c)*224 + ph*16 + ii)*224 + pw*16 + jj];
}

// ---------------- tok = feat + pb + pos ; cls row = cls + pos ----------------
__global__ void add_pos_kernel(float* __restrict__ tok, const float* __restrict__ pb,
                               const float* __restrict__ pos, const float* __restrict__ cls)
{
    const int idx = blockIdx.x*256 + threadIdx.x;
    if (idx >= NTOK*D_) return;
    const int dd = idx % D_;
    const int row = idx / D_;
    const int p = row % L_;
    if (p == 0) tok[idx] = cls[dd] + pos[dd];
    else        tok[idx] += pb[dd] + pos[p*D_ + dd];
}

// ---------------- layernorm over last dim 384, one wave per row ----------------
template<typename OUT_T>
__global__ void ln_kernel(const float* __restrict__ x, const float* __restrict__ w,
                          const float* __restrict__ b, OUT_T* __restrict__ out,
                          int rows, int xstride, int ostride)
{
    const int row = blockIdx.x*blockDim.y + threadIdx.y;
    if (row >= rows) return;
    const int lane = threadIdx.x;
    const float* xr = x + (long)row*xstride;
    float v[6]; float s = 0.f;
    #pragma unroll
    for (int i = 0; i < 6; ++i) { v[i] = xr[lane + 64*i]; s += v[i]; }
    #pragma unroll
    for (int o = 32; o; o >>= 1) s += __shfl_xor(s, o, 64);
    const float mu = s * (1.f/384.f);
    float var = 0.f;
    #pragma unroll
    for (int i = 0; i < 6; ++i) { float d = v[i]-mu; var += d*d; }
    #pragma unroll
    for (int o = 32; o; o >>= 1) var += __shfl_xor(var, o, 64);
    const float rstd = rsqrtf(var*(1.f/384.f) + 1e-5f);
    OUT_T* orow = out + (long)row*ostride;
    #pragma unroll
    for (int i = 0; i < 6; ++i) { int c = lane + 64*i; orow[c] = (OUT_T)((v[i]-mu)*rstd*w[c] + b[c]); }
}

// ---------------- bf16 MFMA GEMM:  C[m,n] (+)= A[m,:K] . B[n,:K]  (B stored [N][K]) ----------------
// BMx128 tile, BK=32, 256 threads.  BM=128: 4 waves 2x2 of 64x64.  BM=64: 4 waves of 64x32.
template<int BM, int ACC, typename CT>
__global__ __launch_bounds__(256)
void gemm_bf16_kernel(const bf16* __restrict__ A, const bf16* __restrict__ B,
                      CT* __restrict__ C, int M, int N, int K)
{
    constexpr int ASLABS = BM/16;
    constexpr int NJ = (BM == 128) ? 4 : 2;
    __shared__ bf16 As[BM*32];
    __shared__ bf16 Bs[128*32];
    const int tid  = threadIdx.x;
    const int wave = tid >> 6, lane = tid & 63;
    const int bm = blockIdx.x*BM, bn = blockIdx.y*128;
    const int wm = (BM == 128) ? (wave>>1)*64 : 0;
    const int wn = (BM == 128) ? (wave&1)*64 : wave*32;
    floatx4 acc[4][NJ];
    #pragma unroll
    for (int i=0;i<4;++i)
        #pragma unroll
        for (int j=0;j<NJ;++j) acc[i][j] = (floatx4){0.f,0.f,0.f,0.f};

    const int lrow = lane >> 2;          // 0..15 (row within 16-row slab)
    const int lcol = (lane & 3) * 8;     // bf16 element col offset
    const int am = lane & 15, ak = (lane>>4)*8;

    for (int k0 = 0; k0 < K; k0 += 32) {
        #pragma unroll
        for (int s = wave; s < ASLABS + 8; s += 4) {
            if (s < ASLABS) {
                const bf16* ga = A + (long)(bm + s*16 + lrow)*K + k0 + lcol;
                __builtin_amdgcn_global_load_lds(
                    (const __attribute__((address_space(1))) void*)ga,
                    (__attribute__((address_space(3))) void*)(As + s*512), 16, 0, 0);
            } else {
                const int s2 = s - ASLABS;
                const bf16* gb = B + (long)(bn + s2*16 + lrow)*K + k0 + lcol;
                __builtin_amdgcn_global_load_lds(
                    (const __attribute__((address_space(1))) void*)gb,
                    (__attribute__((address_space(3))) void*)(Bs + s2*512), 16, 0, 0);
            }
        }
        __syncthreads();
        bf16x8 af[4], bff[NJ];
        #pragma unroll
        for (int i=0;i<4;++i) af[i]  = *(const bf16x8*)(As + (wm + i*16 + am)*32 + ak);
        #pragma unroll
        for (int j=0;j<NJ;++j) bff[j] = *(const bf16x8*)(Bs + (wn + j*16 + am)*32 + ak);
        #pragma unroll
        for (int i=0;i<4;++i)
            #pragma unroll
            for (int j=0;j<NJ;++j)
                acc[i][j] = __builtin_amdgcn_mfma_f32_16x16x32_bf16(af[i], bff[j], acc[i][j], 0, 0, 0);
        __syncthreads();
    }
    // epilogue: C/D layout col=lane&15, row=(lane>>4)*4+reg
    const int rbase = bm + wm + (lane>>4)*4;
    const int cbase = bn + wn + (lane & 15);
    #pragma unroll
    for (int i = 0; i < 4; ++i) {
        #pragma unroll
        for (int r = 0; r < 4; ++r) {
            const int row = rbase + i*16 + r;
            if (row >= M) continue;
            #pragma unroll
            for (int j = 0; j < NJ; ++j) {
                const long idx = (long)row*N + cbase + j*16;
                if (ACC) C[idx] += acc[i][j][r];
                else     C[idx]  = (CT)acc[i][j][r];
            }
        }
    }
}

// ---------------- causal depthwise conv1d (DCONV=4) + bias + silu -> bf16, x2 vectorized ----------------
__global__ void conv_silu_kernel(const bf16* __restrict__ xz, const float* __restrict__ cw,
                                 const float* __restrict__ cb, bf16* __restrict__ out)
{
    const int idx = blockIdx.x*256 + threadIdx.x;      // over NTOK*DI/2
    if (idx >= NTOK*(DI/2)) return;
    const int dp = idx % (DI/2);
    const int bl = idx / (DI/2);
    const int l  = bl % L_;
    const int di = dp*2;
    const long rowbase = (long)(bl - l)*(2*DI) + di;
    const float4 wa = *(const float4*)(cw + di*4);
    const float4 wb = *(const float4*)(cw + di*4 + 4);
    float a0 = cb[di], a1 = cb[di+1];
    #pragma unroll
    for (int k = 0; k < 4; ++k) {
        const int lt = l - 3 + k;
        if (lt >= 0) {
            const bf16x2 xv = *(const bf16x2*)(xz + rowbase + (long)lt*(2*DI));
            const float w0 = (k==0)?wa.x:(k==1)?wa.y:(k==2)?wa.z:wa.w;
            const float w1 = (k==0)?wb.x:(k==1)?wb.y:(k==2)?wb.z:wb.w;
            a0 += w0 * (float)xv[0];
            a1 += w1 * (float)xv[1];
        }
    }
    bf16x2 r;
    r[0] = (bf16)(a0 * sigmoidf_(a0));
    r[1] = (bf16)(a1 * sigmoidf_(a1));
    *(bf16x2*)(out + (long)bl*DI + di) = r;
}

// ---------------- fused dt_proj + selective scan + D-skip + gate -> y bf16 ----------------
// block 256 = 16 di x 16 s (wave: 4 di-groups x 16 s). grid (DI/16, B_).
// Sequential chain is ONLY h = a*h + b (16 dependent FMAs per 16-token chunk).
__global__ __launch_bounds__(256)
void scan_kernel(const bf16* __restrict__ xbc, const float* __restrict__ xdbl,
                 const bf16* __restrict__ xz, const float* __restrict__ A_log,
                 const float* __restrict__ Dp, const float* __restrict__ dtw,
                 const float* __restrict__ dtb, bf16* __restrict__ y)
{
    const int tid  = threadIdx.x;
    const int w    = tid >> 6, lane = tid & 63;
    const int s    = lane & 15;        // state index (compute) / token index (dt+write roles)
    const int dlq  = lane >> 4;        // 0..3
    const int dl   = w*4 + dlq;        // block-local di 0..15
    const int di0  = blockIdx.x*16;
    const int di   = di0 + dl;
    const int b    = blockIdx.y;

    const float A_s = -__expf(A_log[di*DS + s]);
    const float Dv  = Dp[di];
    float wdt[24];
    #pragma unroll
    for (int r = 0; r < 24; ++r) wdt[r] = dtw[di*DTR + r];
    const float bias = dtb[di];

    __shared__ float sh_row[16][64];    // xdbl rows (56 valid): dt_raw 0:24 | B 24:40 | C 40:56
    __shared__ float sh_x[16][16];      // [t][dl]
    __shared__ float sh_z[16][16];
    __shared__ float sh_dt[4][16][4];   // [wave][t][dlq]  (wave-private)

    float h = 0.f;
    for (int l0 = 0; l0 < L_; l0 += 16) {
        const int CH = (L_ - l0 < 16) ? (L_ - l0) : 16;
        const long blo0 = (long)b*L_ + l0;
        __syncthreads();
        #pragma unroll
        for (int it = 0; it < 4; ++it) {
            const int idx = tid + it*256;
            const int t = idx >> 6, e = idx & 63;
            float vv = 0.f;
            if (t < CH && e < 56) vv = xdbl[(blo0 + t)*128 + e];
            sh_row[t][e] = vv;
        }
        {
            const int t = tid >> 4, e = tid & 15;
            float xvv = 0.f, zvv = 0.f;
            if (t < CH) {
                xvv = (float)xbc[(blo0 + t)*DI + di0 + e];
                zvv = (float)xz[(blo0 + t)*(2*DI) + DI + di0 + e];
            }
            sh_x[t][e] = xvv;
            sh_z[t][e] = zvv;
        }
        __syncthreads();
        // wave-local dt: lane computes dt for (token t = s, its dl). Same-wave LDS -> no barrier.
        {
            float acc = bias;
            #pragma unroll
            for (int r = 0; r < 24; ++r) acc += sh_row[s][r] * wdt[r];
            sh_dt[w][s][dlq] = (acc > 20.f) ? acc : __logf(1.f + __expf(acc));
        }
        float v[16];
        #pragma unroll
        for (int t = 0; t < 16; ++t) {
            const float dtv = sh_dt[w][t][dlq];
            const float a   = __expf(dtv * A_s);
            const float bx  = dtv * sh_x[t][dl] * sh_row[t][24 + s];
            h = fmaf(a, h, bx);
            v[t] = h * sh_row[t][40 + s];
        }
        // reduce-scatter over the 16 s-lanes: lane s ends with total for token t=s in v[0]
        #pragma unroll
        for (int m = 8; m >= 1; m >>= 1) {
            const bool hi = (s & m) != 0;
            #pragma unroll
            for (int i = 0; i < m; ++i) {
                const float keep = hi ? v[i + m] : v[i];
                const float send = hi ? v[i] : v[i + m];
                v[i] = keep + __shfl_xor(send, m, 64);
            }
        }
        if (s < CH) {
            const float xvv = sh_x[s][dl];
            const float z   = sh_z[s][dl];
            y[(blo0 + s)*DI + di] = (bf16)((v[0] + Dv*xvv) * z * sigmoidf_(z));
        }
    }
}

// ---------------- head bias + copy from padded GEMM output ----------------
__global__ void head_bias_kernel(const float* __restrict__ chead, const float* __restrict__ hb,
                                 float* __restrict__ out)
{
    const int idx = blockIdx.x*256 + threadIdx.x;
    if (idx >= B_*NCLS) return;
    const int n = idx % NCLS, b = idx / NCLS;
    out[idx] = chead[(long)b*1024 + n] + hb[n];
}

extern "C" void kernel_launch(void* const* d_in, const int* in_sizes, int n_in,
                              void* d_out, int out_size, void* d_ws, size_t ws_size,
                              hipStream_t stream)
{
    const float* x       = (const float*)d_in[0];
    const float* patch_w = (const float*)d_in[1];
    const float* patch_b = (const float*)d_in[2];
    const float* cls_tok = (const float*)d_in[3];
    const float* pos_emb = (const float*)d_in[4];
    const float* ln_w    = (const float*)d_in[5];
    const float* ln_b    = (const float*)d_in[6];
    const float* in_w    = (const float*)d_in[7];
    const float* conv_w  = (const float*)d_in[8];
    const float* conv_b  = (const float*)d_in[9];
    const float* xp_w    = (const float*)d_in[10];
    const float* dt_w    = (const float*)d_in[11];
    const float* dt_b    = (const float*)d_in[12];
    const float* A_log   = (const float*)d_in[13];
    const float* D_par   = (const float*)d_in[14];
    const float* out_w   = (const float*)d_in[15];
    const float* normf_w = (const float*)d_in[16];
    const float* normf_b = (const float*)d_in[17];
    const float* head_w  = (const float*)d_in[18];
    const float* head_b  = (const float*)d_in[19];
    float* out = (float*)d_out;

    // workspace layout (~106 MB)
    char* p = (char*)d_ws;
    float* tok    = (float*)p;  p += (long)NTOK*D_*4;          // 9.68 MB
    bf16*  xz_b   = (bf16*)p;   p += (long)MPAD*2*DI*2;        // 19.66 MB
    bf16*  xbc_b  = (bf16*)p;   p += (long)MPAD*DI*2;          // 9.83 MB
    bf16*  y_b    = (bf16*)p;   p += (long)MPAD*DI*2;          // 9.83 MB (aliased: im2col patches)
    float* xdbl   = (float*)p;  p += (long)MPAD*128*4;         // 3.28 MB
    bf16*  xnorm_b= (bf16*)p;   p += (long)MPAD*D_*2;          // 4.92 MB
    bf16*  ln0_b  = (bf16*)p;   p += (long)64*D_*2;
    float* chead  = (float*)p;  p += (long)64*1024*4;
    bf16*  w_in_b = (bf16*)p;   p += (long)DEPTH*INW_E*2;      // 28.3 MB
    bf16*  w_out_b= (bf16*)p;   p += (long)DEPTH*OUTW_E*2;     // 14.2 MB
    bf16*  w_xp_b = (bf16*)p;   p += (long)DEPTH*XPW_E*2;      // 4.72 MB
    bf16*  pw_b   = (bf16*)p;   p += (long)PW_E*2;             // 0.59 MB
    bf16*  hw_b   = (bf16*)p;   p += (long)HW_E*2;             // 0.79 MB
    bf16*  patches = y_b;

    const long WCONV_E = (long)DEPTH*(INW_E + OUTW_E + XPW_E) + PW_E + HW_E;
    wconv_all_kernel<<<dim3((WCONV_E + 255)/256), 256, 0, stream>>>(
        in_w, out_w, xp_w, patch_w, head_w, w_in_b, w_out_b, w_xp_b, pw_b, hw_b);

    im2col_kernel<<<dim3(((long)B_*196*768 + 255)/256), 256, 0, stream>>>(x, patches);
    gemm_bf16_kernel<64,0,float><<<dim3(100, 3), 256, 0, stream>>>(
        patches, pw_b, tok, NTOK, D_, 768);
    add_pos_kernel<<<dim3((NTOK*D_ + 255)/256), 256, 0, stream>>>(tok, patch_b, pos_emb, cls_tok);

    for (int layer = 0; layer < DEPTH; ++layer) {
        ln_kernel<bf16><<<dim3(NTOK/4), dim3(64,4), 0, stream>>>(
            tok, ln_w + layer*D_, ln_b + layer*D_, xnorm_b, NTOK, D_, D_);
        gemm_bf16_kernel<128,0,bf16><<<dim3(50, 12), 256, 0, stream>>>(
            xnorm_b, w_in_b + (long)layer*INW_E, xz_b, NTOK, 2*DI, D_);
        conv_silu_kernel<<<dim3((NTOK*(DI/2) + 255)/256), 256, 0, stream>>>(
            xz_b, conv_w + layer*DI*DCONV, conv_b + layer*DI, xbc_b);
        gemm_bf16_kernel<64,0,float><<<dim3(100, 1), 256, 0, stream>>>(
            xbc_b, w_xp_b + (long)layer*XPW_E, xdbl, NTOK, 128, DI);
        scan_kernel<<<dim3(DI/16, B_), 256, 0, stream>>>(
            xbc_b, xdbl, xz_b, A_log + layer*DI*DS, D_par + layer*DI,
            dt_w + layer*DI*DTR, dt_b + layer*DI, y_b);
        gemm_bf16_kernel<64,1,float><<<dim3(100, 3), 256, 0, stream>>>(
            y_b, w_out_b + (long)layer*OUTW_E, tok, NTOK, D_, DI);
    }

    ln_kernel<bf16><<<dim3(8), dim3(64,4), 0, stream>>>(tok, normf_w, normf_b, ln0_b, B_, L_*D_, D_);
    gemm_bf16_kernel<64,0,float><<<dim3(1, 8), 256, 0, stream>>>(
        ln0_b, hw_b, chead, 64, 1024, D_);
    head_bias_kernel<<<dim3((B_*NCLS + 255)/256), 256, 0, stream>>>(chead, head_b, out);
}

// Round 5
// 6189.527 us; speedup vs baseline: 2.6751x; 1.0964x over previous
//
#include <hip/hip_runtime.h>
#include <math.h>

// ---- problem dims ----
#define B_    32
#define D_    384
#define DEPTH 24
#define DI    768
#define DS    16
#define DCONV 4
#define DTR   24
#define L_    197
#define NCLS  1000
#define NTOK  (B_*L_)   // 6304
#define MPAD  6400      // padded row count for GEMM A buffers

typedef __bf16 bf16;
typedef __bf16 bf16x2 __attribute__((ext_vector_type(2)));
typedef __bf16 bf16x8 __attribute__((ext_vector_type(8)));
typedef float  floatx4 __attribute__((ext_vector_type(4)));

#define INW_E  (1536*384)
#define OUTW_E (384*768)
#define XPW_E  (128*768)
#define PW_E   (384*768)
#define HW_E   (1024*384)

__device__ __forceinline__ float sigmoidf_(float x){ return 1.f/(1.f+__expf(-x)); }

// ---------------- all-weights fp32 -> bf16 conversion (once per call) ----------------
__global__ void wconv_all_kernel(const float* __restrict__ in_w, const float* __restrict__ out_w,
                                 const float* __restrict__ xp_w, const float* __restrict__ patch_w,
                                 const float* __restrict__ head_w,
                                 bf16* __restrict__ w_in_b, bf16* __restrict__ w_out_b,
                                 bf16* __restrict__ w_xp_b, bf16* __restrict__ pw_b,
                                 bf16* __restrict__ hw_b)
{
    long idx = (long)blockIdx.x*256 + threadIdx.x;
    if (idx < (long)DEPTH*INW_E) { w_in_b[idx] = (bf16)in_w[idx]; return; }
    idx -= (long)DEPTH*INW_E;
    if (idx < (long)DEPTH*OUTW_E) { w_out_b[idx] = (bf16)out_w[idx]; return; }
    idx -= (long)DEPTH*OUTW_E;
    if (idx < (long)DEPTH*XPW_E) {
        const int l = idx / XPW_E, loc = idx % XPW_E;
        w_xp_b[idx] = (loc < 56*768) ? (bf16)xp_w[(long)l*56*768 + loc] : (bf16)0.f;
        return;
    }
    idx -= (long)DEPTH*XPW_E;
    if (idx < PW_E) { pw_b[idx] = (bf16)patch_w[idx]; return; }
    idx -= PW_E;
    if (idx < HW_E) hw_b[idx] = (idx < (long)NCLS*384) ? (bf16)head_w[idx] : (bf16)0.f;
}

// ---------------- per-layer composite dt weight: W2[o,i] = sum_r dtw[o,r]*xp_w[r,i] ----------------
// grid 768 (di_out), 256 threads
__global__ void w2_compose_kernel(const float* __restrict__ dtw, const float* __restrict__ xpw,
                                  bf16* __restrict__ w2)
{
    __shared__ float sw[24];
    const int o = blockIdx.x;
    if (threadIdx.x < 24) sw[threadIdx.x] = dtw[(long)o*DTR + threadIdx.x];
    __syncthreads();
    for (int i = threadIdx.x; i < DI; i += 256) {
        float acc = 0.f;
        #pragma unroll
        for (int r = 0; r < 24; ++r) acc += sw[r]*xpw[r*DI + i];
        w2[(long)o*DI + i] = (bf16)acc;
    }
}

// ---------------- im2col: x[B,3,224,224] -> patches[b*197+1+pi, 768] bf16 ----------------
__global__ void im2col_kernel(const float* __restrict__ x, bf16* __restrict__ patches)
{
    const long idx = (long)blockIdx.x*256 + threadIdx.x;
    if (idx >= (long)B_*196*768) return;
    const int k = idx % 768;
    const int prow = idx / 768;
    const int b = prow / 196, pi = prow % 196;
    const int ph = pi / 14, pw = pi % 14;
    const int c = k >> 8, rem = k & 255, ii = rem >> 4, jj = rem & 15;
    patches[((long)(b*L_ + 1 + pi))*768 + k] =
        (bf16)x[(((long)b*3 + c)*224 + ph*16 + ii)*224 + pw*16 + jj];
}

// ---------------- tok = feat + pb + pos ; cls row = cls + pos ----------------
__global__ void add_pos_kernel(float* __restrict__ tok, const float* __restrict__ pb,
                               const float* __restrict__ pos, const float* __restrict__ cls)
{
    const int idx = blockIdx.x*256 + threadIdx.x;
    if (idx >= NTOK*D_) return;
    const int dd = idx % D_;
    const int row = idx / D_;
    const int p = row % L_;
    if (p == 0) tok[idx] = cls[dd] + pos[dd];
    else        tok[idx] += pb[dd] + pos[p*D_ + dd];
}

// ---------------- layernorm over last dim 384, one wave per row ----------------
template<typename OUT_T>
__global__ void ln_kernel(const float* __restrict__ x, const float* __restrict__ w,
                          const float* __restrict__ b, OUT_T* __restrict__ out,
                          int rows, int xstride, int ostride)
{
    const int row = blockIdx.x*blockDim.y + threadIdx.y;
    if (row >= rows) return;
    const int lane = threadIdx.x;
    const float* xr = x + (long)row*xstride;
    float v[6]; float s = 0.f;
    #pragma unroll
    for (int i = 0; i < 6; ++i) { v[i] = xr[lane + 64*i]; s += v[i]; }
    #pragma unroll
    for (int o = 32; o; o >>= 1) s += __shfl_xor(s, o, 64);
    const float mu = s * (1.f/384.f);
    float var = 0.f;
    #pragma unroll
    for (int i = 0; i < 6; ++i) { float d = v[i]-mu; var += d*d; }
    #pragma unroll
    for (int o = 32; o; o >>= 1) var += __shfl_xor(var, o, 64);
    const float rstd = rsqrtf(var*(1.f/384.f) + 1e-5f);
    OUT_T* orow = out + (long)row*ostride;
    #pragma unroll
    for (int i = 0; i < 6; ++i) { int c = lane + 64*i; orow[c] = (OUT_T)((v[i]-mu)*rstd*w[c] + b[c]); }
}

// ---------------- bf16 MFMA GEMM:  C[m,n] (+)= A[m,:K] . B[n,:K]  (B stored [N][K]) ----------------
// BMx128 tile, BK=32, 256 threads.  BM=128: 4 waves 2x2 of 64x64.  BM=64: 4 waves of 64x32.
template<int BM, int ACC, typename CT>
__global__ __launch_bounds__(256)
void gemm_bf16_kernel(const bf16* __restrict__ A, const bf16* __restrict__ B,
                      CT* __restrict__ C, int M, int N, int K)
{
    constexpr int ASLABS = BM/16;
    constexpr int NJ = (BM == 128) ? 4 : 2;
    __shared__ bf16 As[BM*32];
    __shared__ bf16 Bs[128*32];
    const int tid  = threadIdx.x;
    const int wave = tid >> 6, lane = tid & 63;
    const int bm = blockIdx.x*BM, bn = blockIdx.y*128;
    const int wm = (BM == 128) ? (wave>>1)*64 : 0;
    const int wn = (BM == 128) ? (wave&1)*64 : wave*32;
    floatx4 acc[4][NJ];
    #pragma unroll
    for (int i=0;i<4;++i)
        #pragma unroll
        for (int j=0;j<NJ;++j) acc[i][j] = (floatx4){0.f,0.f,0.f,0.f};

    const int lrow = lane >> 2;          // 0..15 (row within 16-row slab)
    const int lcol = (lane & 3) * 8;     // bf16 element col offset
    const int am = lane & 15, ak = (lane>>4)*8;

    for (int k0 = 0; k0 < K; k0 += 32) {
        #pragma unroll
        for (int s = wave; s < ASLABS + 8; s += 4) {
            if (s < ASLABS) {
                const bf16* ga = A + (long)(bm + s*16 + lrow)*K + k0 + lcol;
                __builtin_amdgcn_global_load_lds(
                    (const __attribute__((address_space(1))) void*)ga,
                    (__attribute__((address_space(3))) void*)(As + s*512), 16, 0, 0);
            } else {
                const int s2 = s - ASLABS;
                const bf16* gb = B + (long)(bn + s2*16 + lrow)*K + k0 + lcol;
                __builtin_amdgcn_global_load_lds(
                    (const __attribute__((address_space(1))) void*)gb,
                    (__attribute__((address_space(3))) void*)(Bs + s2*512), 16, 0, 0);
            }
        }
        __syncthreads();
        bf16x8 af[4], bff[NJ];
        #pragma unroll
        for (int i=0;i<4;++i) af[i]  = *(const bf16x8*)(As + (wm + i*16 + am)*32 + ak);
        #pragma unroll
        for (int j=0;j<NJ;++j) bff[j] = *(const bf16x8*)(Bs + (wn + j*16 + am)*32 + ak);
        #pragma unroll
        for (int i=0;i<4;++i)
            #pragma unroll
            for (int j=0;j<NJ;++j)
                acc[i][j] = __builtin_amdgcn_mfma_f32_16x16x32_bf16(af[i], bff[j], acc[i][j], 0, 0, 0);
        __syncthreads();
    }
    // epilogue: C/D layout col=lane&15, row=(lane>>4)*4+reg
    const int rbase = bm + wm + (lane>>4)*4;
    const int cbase = bn + wn + (lane & 15);
    #pragma unroll
    for (int i = 0; i < 4; ++i) {
        #pragma unroll
        for (int r = 0; r < 4; ++r) {
            const int row = rbase + i*16 + r;
            if (row >= M) continue;
            #pragma unroll
            for (int j = 0; j < NJ; ++j) {
                const long idx = (long)row*N + cbase + j*16;
                if (ACC) C[idx] += acc[i][j][r];
                else     C[idx]  = (CT)acc[i][j][r];
            }
        }
    }
}

// ---------------- causal depthwise conv1d (DCONV=4) + bias + silu -> bf16, x2 vectorized ----------------
__global__ void conv_silu_kernel(const bf16* __restrict__ xz, const float* __restrict__ cw,
                                 const float* __restrict__ cb, bf16* __restrict__ out)
{
    const int idx = blockIdx.x*256 + threadIdx.x;      // over NTOK*DI/2
    if (idx >= NTOK*(DI/2)) return;
    const int dp = idx % (DI/2);
    const int bl = idx / (DI/2);
    const int l  = bl % L_;
    const int di = dp*2;
    const long rowbase = (long)(bl - l)*(2*DI) + di;
    const float4 wa = *(const float4*)(cw + di*4);
    const float4 wb = *(const float4*)(cw + di*4 + 4);
    float a0 = cb[di], a1 = cb[di+1];
    #pragma unroll
    for (int k = 0; k < 4; ++k) {
        const int lt = l - 3 + k;
        if (lt >= 0) {
            const bf16x2 xv = *(const bf16x2*)(xz + rowbase + (long)lt*(2*DI));
            const float w0 = (k==0)?wa.x:(k==1)?wa.y:(k==2)?wa.z:wa.w;
            const float w1 = (k==0)?wb.x:(k==1)?wb.y:(k==2)?wb.z:wb.w;
            a0 += w0 * (float)xv[0];
            a1 += w1 * (float)xv[1];
        }
    }
    bf16x2 r;
    r[0] = (bf16)(a0 * sigmoidf_(a0));
    r[1] = (bf16)(a1 * sigmoidf_(a1));
    *(bf16x2*)(out + (long)bl*DI + di) = r;
}

// ---------------- selective scan (dt precomputed via GEMM) + D-skip + gate -> y bf16 ----------------
// block 256 = 16 di x 16 s. grid (DI/16, B_). Serial chain: only h = a*h + bx.
// LDS: interleaved float2 pairs, row stride 34 -> conflict-free ds_read_b64.
__global__ __launch_bounds__(256)
void scan_kernel(const bf16* __restrict__ xbc, const float* __restrict__ xdbl,
                 const bf16* __restrict__ xz, const bf16* __restrict__ dtr,
                 const float* __restrict__ A_log, const float* __restrict__ Dp,
                 const float* __restrict__ dtb, bf16* __restrict__ y)
{
    const int tid  = threadIdx.x;
    const int w    = tid >> 6, lane = tid & 63;
    const int s    = lane & 15;        // state index / write-token index
    const int dlq  = lane >> 4;        // 0..3
    const int dl   = w*4 + dlq;        // block-local di 0..15
    const int di0  = blockIdx.x*16;
    const int di   = di0 + dl;
    const int b    = blockIdx.y;

    const float A_s = -__expf(A_log[di*DS + s]);
    const float Dv  = Dp[di];
    // staging roles (fixed per thread)
    const int st = tid >> 4, se = tid & 15;
    const float bias = dtb[di0 + se];

    __shared__ float sh_bc[16][34];    // [t][2s]=B, [2s+1]=C
    __shared__ float sh_dd[16][34];    // [t][2e]=dt, [2e+1]=dt*x
    __shared__ float sh_xz[16][34];    // [t][2e]=x,  [2e+1]=z

    float h = 0.f;
    for (int l0 = 0; l0 < L_; l0 += 16) {
        const int CH = (L_ - l0 < 16) ? (L_ - l0) : 16;
        const long blo0 = (long)b*L_ + l0;
        __syncthreads();
        // stage B,C (512 values, 2 per thread), xdbl cols 24..56
        #pragma unroll
        for (int it = 0; it < 2; ++it) {
            const int idx = tid + it*256;
            const int tt = idx >> 5, ee = idx & 31;
            float vv = 0.f;
            if (tt < CH) vv = xdbl[(blo0 + tt)*128 + 24 + ee];
            sh_bc[tt][2*(ee & 15) + (ee >> 4)] = vv;
        }
        // stage x, z, dt (softplus), dt*x
        {
            float xv = 0.f, zv = 0.f, dtv = 0.f;
            if (st < CH) {
                xv = (float)xbc[(blo0 + st)*DI + di0 + se];
                zv = (float)xz[(blo0 + st)*(2*DI) + DI + di0 + se];
                const float dr = (float)dtr[(blo0 + st)*DI + di0 + se] + bias;
                dtv = (dr > 20.f) ? dr : log1pf(__expf(dr));
            }
            sh_xz[st][2*se]   = xv;
            sh_xz[st][2*se+1] = zv;
            sh_dd[st][2*se]   = dtv;
            sh_dd[st][2*se+1] = dtv*xv;
        }
        __syncthreads();
        float v[16];
        #pragma unroll
        for (int t = 0; t < 16; ++t) {
            const float2 dd = *(const float2*)&sh_dd[t][2*dl];
            const float2 bc = *(const float2*)&sh_bc[t][2*s];
            const float a = __expf(dd.x * A_s);
            h = fmaf(a, h, dd.y * bc.x);
            v[t] = h * bc.y;
        }
        // reduce-scatter over the 16 s-lanes: lane s ends with total for token t=s in v[0]
        #pragma unroll
        for (int m = 8; m >= 1; m >>= 1) {
            const bool hi = (s & m) != 0;
            #pragma unroll
            for (int i = 0; i < m; ++i) {
                const float keep = hi ? v[i + m] : v[i];
                const float send = hi ? v[i] : v[i + m];
                v[i] = keep + __shfl_xor(send, m, 64);
            }
        }
        if (s < CH) {
            const float2 xzv = *(const float2*)&sh_xz[s][2*dl];
            y[(blo0 + s)*DI + di] = (bf16)((v[0] + Dv*xzv.x) * xzv.y * sigmoidf_(xzv.y));
        }
    }
}

// ---------------- head bias + copy from padded GEMM output ----------------
__global__ void head_bias_kernel(const float* __restrict__ chead, const float* __restrict__ hb,
                                 float* __restrict__ out)
{
    const int idx = blockIdx.x*256 + threadIdx.x;
    if (idx >= B_*NCLS) return;
    const int n = idx % NCLS, b = idx / NCLS;
    out[idx] = chead[(long)b*1024 + n] + hb[n];
}

extern "C" void kernel_launch(void* const* d_in, const int* in_sizes, int n_in,
                              void* d_out, int out_size, void* d_ws, size_t ws_size,
                              hipStream_t stream)
{
    const float* x       = (const float*)d_in[0];
    const float* patch_w = (const float*)d_in[1];
    const float* patch_b = (const float*)d_in[2];
    const float* cls_tok = (const float*)d_in[3];
    const float* pos_emb = (const float*)d_in[4];
    const float* ln_w    = (const float*)d_in[5];
    const float* ln_b    = (const float*)d_in[6];
    const float* in_w    = (const float*)d_in[7];
    const float* conv_w  = (const float*)d_in[8];
    const float* conv_b  = (const float*)d_in[9];
    const float* xp_w    = (const float*)d_in[10];
    const float* dt_w    = (const float*)d_in[11];
    const float* dt_b    = (const float*)d_in[12];
    const float* A_log   = (const float*)d_in[13];
    const float* D_par   = (const float*)d_in[14];
    const float* out_w   = (const float*)d_in[15];
    const float* normf_w = (const float*)d_in[16];
    const float* normf_b = (const float*)d_in[17];
    const float* head_w  = (const float*)d_in[18];
    const float* head_b  = (const float*)d_in[19];
    float* out = (float*)d_out;

    // workspace layout (~107 MB)
    char* p = (char*)d_ws;
    float* tok    = (float*)p;  p += (long)NTOK*D_*4;          // 9.68 MB
    bf16*  xz_b   = (bf16*)p;   p += (long)MPAD*2*DI*2;        // 19.66 MB
    bf16*  xbc_b  = (bf16*)p;   p += (long)MPAD*DI*2;          // 9.83 MB
    bf16*  y_b    = (bf16*)p;   p += (long)MPAD*DI*2;          // 9.83 MB (aliases im2col patches AND dt_raw)
    float* xdbl   = (float*)p;  p += (long)MPAD*128*4;         // 3.28 MB
    bf16*  xnorm_b= (bf16*)p;   p += (long)MPAD*D_*2;          // 4.92 MB
    bf16*  ln0_b  = (bf16*)p;   p += (long)64*D_*2;
    float* chead  = (float*)p;  p += (long)64*1024*4;
    bf16*  w2_b   = (bf16*)p;   p += (long)DI*DI*2;            // 1.18 MB (per-layer composite dt weight)
    bf16*  w_in_b = (bf16*)p;   p += (long)DEPTH*INW_E*2;      // 28.3 MB
    bf16*  w_out_b= (bf16*)p;   p += (long)DEPTH*OUTW_E*2;     // 14.2 MB
    bf16*  w_xp_b = (bf16*)p;   p += (long)DEPTH*XPW_E*2;      // 4.72 MB
    bf16*  pw_b   = (bf16*)p;   p += (long)PW_E*2;             // 0.59 MB
    bf16*  hw_b   = (bf16*)p;   p += (long)HW_E*2;             // 0.79 MB
    bf16*  patches = y_b;
    bf16*  dtr_b   = y_b;   // dt_raw aliases y: scan reads/writes identical (b, di-slice) chunks in order

    const long WCONV_E = (long)DEPTH*(INW_E + OUTW_E + XPW_E) + PW_E + HW_E;
    wconv_all_kernel<<<dim3((WCONV_E + 255)/256), 256, 0, stream>>>(
        in_w, out_w, xp_w, patch_w, head_w, w_in_b, w_out_b, w_xp_b, pw_b, hw_b);

    im2col_kernel<<<dim3(((long)B_*196*768 + 255)/256), 256, 0, stream>>>(x, patches);
    gemm_bf16_kernel<64,0,float><<<dim3(100, 3), 256, 0, stream>>>(
        patches, pw_b, tok, NTOK, D_, 768);
    add_pos_kernel<<<dim3((NTOK*D_ + 255)/256), 256, 0, stream>>>(tok, patch_b, pos_emb, cls_tok);

    for (int layer = 0; layer < DEPTH; ++layer) {
        ln_kernel<bf16><<<dim3(NTOK/4), dim3(64,4), 0, stream>>>(
            tok, ln_w + layer*D_, ln_b + layer*D_, xnorm_b, NTOK, D_, D_);
        gemm_bf16_kernel<128,0,bf16><<<dim3(50, 12), 256, 0, stream>>>(
            xnorm_b, w_in_b + (long)layer*INW_E, xz_b, NTOK, 2*DI, D_);
        conv_silu_kernel<<<dim3((NTOK*(DI/2) + 255)/256), 256, 0, stream>>>(
            xz_b, conv_w + layer*DI*DCONV, conv_b + layer*DI, xbc_b);
        gemm_bf16_kernel<64,0,float><<<dim3(100, 1), 256, 0, stream>>>(
            xbc_b, w_xp_b + (long)layer*XPW_E, xdbl, NTOK, 128, DI);
        w2_compose_kernel<<<dim3(DI), 256, 0, stream>>>(
            dt_w + (long)layer*DI*DTR, xp_w + (long)layer*56*768, w2_b);
        gemm_bf16_kernel<128,0,bf16><<<dim3(50, 6), 256, 0, stream>>>(
            xbc_b, w2_b, dtr_b, NTOK, DI, DI);
        scan_kernel<<<dim3(DI/16, B_), 256, 0, stream>>>(
            xbc_b, xdbl, xz_b, dtr_b, A_log + layer*DI*DS, D_par + layer*DI,
            dt_b + layer*DI, y_b);
        gemm_bf16_kernel<64,1,float><<<dim3(100, 3), 256, 0, stream>>>(
            y_b, w_out_b + (long)layer*OUTW_E, tok, NTOK, D_, DI);
    }

    ln_kernel<bf16><<<dim3(8), dim3(64,4), 0, stream>>>(tok, normf_w, normf_b, ln0_b, B_, L_*D_, D_);
    gemm_bf16_kernel<64,0,float><<<dim3(1, 8), 256, 0, stream>>>(
        ln0_b, hw_b, chead, 64, 1024, D_);
    head_bias_kernel<<<dim3((B_*NCLS + 255)/256), 256, 0, stream>>>(chead, head_b, out);
}